// Round 3
// baseline (646.737 us; speedup 1.0000x reference)
//
#include <hip/hip_runtime.h>

typedef unsigned short u16;
typedef unsigned int u32;

#define BB 64
#define FF 4096
#define DD 192
#define HH 768

typedef __attribute__((ext_vector_type(8))) __bf16 bf16x8;
typedef __attribute__((ext_vector_type(4))) float f32x4;

__device__ __forceinline__ float bf2f(u32 u) {
  union { u32 i; float f; } x; x.i = u << 16; return x.f;
}
__device__ __forceinline__ u16 f2bf(float f) {
  __bf16 h = (__bf16)f;
  return __builtin_bit_cast(u16, h);
}
__device__ __forceinline__ u32 pk2bf(float a, float b) {
  return (u32)f2bf(a) | ((u32)f2bf(b) << 16);
}
__device__ __forceinline__ float sigm(float x) { return 1.f / (1.f + __expf(-x)); }

// ---------------------------------------------------------------------------
// Prep: WmodT[n][e] = g[e]*W[e][n] (bf16), s1[n]=sum g*W (bf16-rounded), s0[n]=b@W.
// ---------------------------------------------------------------------------
__global__ void prep_wmod(const float* __restrict__ Wk, const float* __restrict__ Wv,
                          const float* __restrict__ g, const float* __restrict__ bb,
                          u16* __restrict__ wmodT, float* __restrict__ s1,
                          float* __restrict__ s0) {
  int n = blockIdx.x * 64 + threadIdx.x;  // 0..383
  const float* W = (n < DD) ? Wk : Wv;
  int col = (n < DD) ? n : n - DD;
  float a1 = 0.f, a0 = 0.f;
  for (int e = 0; e < DD; ++e) {
    float w = W[e * DD + col];
    u16 h = f2bf(g[e] * w);
    wmodT[n * DD + e] = h;
    a1 += bf2f(h);
    a0 += bb[e] * w;
  }
  s1[n] = a1; s0[n] = a0;
}

// Pack GRU/MLP weights to bf16 e-pairs: dst[((g*E2+e/2)*N + n)*2 + (e&1)].
__global__ void prep_packw(const float* __restrict__ Wih, const float* __restrict__ Whh,
                           const float* __restrict__ W1, const float* __restrict__ W2,
                           u16* __restrict__ pWih, u16* __restrict__ pWhh,
                           u16* __restrict__ pW1, u16* __restrict__ pW2) {
  int which = blockIdx.y;
  int total, N, E;
  const float* src; u16* dst; int srcEmajor;
  if (which < 2) { total = 3 * 576 * 192; N = 576; E = 192; srcEmajor = 0;
                   src = which ? Whh : Wih; dst = which ? pWhh : pWih; }
  else if (which == 2) { total = 3 * 192 * 768; N = 768; E = 192; srcEmajor = 1;
                         src = W1; dst = pW1; }
  else { total = 3 * 768 * 192; N = 192; E = 768; srcEmajor = 1; src = W2; dst = pW2; }
  for (int idx = blockIdx.x * 256 + threadIdx.x; idx < total; idx += gridDim.x * 256) {
    int g = idx / (N * E), rem = idx % (N * E);
    int n, e;
    if (srcEmajor) { e = rem / N; n = rem % N; }    // src[g][e][n]
    else { n = rem / E; e = rem % E; }              // src[g][n][e]
    dst[((g * (E / 2) + (e >> 1)) * N + n) * 2 + (e & 1)] = f2bf(src[idx]);
  }
}

// ---------------------------------------------------------------------------
// Projection: k = LN(x)@Wk, v = LN(x)@Wv, LN folded into epilogue.
// kc_: chunked fragment layout [(b*256+Tg)*24 + u][tok16][8dims] bf16.
// vc_: PV B-fragment layout [((b*128+g32)*12 + nt)*64 + l4*16 + l15][8toks] bf16.
// Block: 256 thr (4 waves), M-tile = 64 tokens; wave = N-quarter (96 cols).
// ---------------------------------------------------------------------------
__global__ __launch_bounds__(256, 4) void proj_kernel(
    const float* __restrict__ feat, const u16* __restrict__ wmodT,
    const float* __restrict__ s1, const float* __restrict__ s0,
    u16* __restrict__ kc_, u16* __restrict__ vc_) {
  __shared__ __align__(16) u16 Atile[64 * 192];   // swizzled bf16; reused as k C-tile
  __shared__ float stats[64 * 2];                 // (mu, rstd)
  int tid = threadIdx.x;
  long tile_base = (long)blockIdx.x * 64;
  int w = tid >> 6, lane = tid & 63;
  // ---- staging: wave w owns rows w*16..+15; 4 lanes per row, shuffle stats ----
  {
    int r = w * 16 + (lane >> 2);
    int p = lane & 3;
    const float4* src = (const float4*)(feat + (tile_base + r) * DD) + p * 12;
    float s = 0.f, s2 = 0.f;
    #pragma unroll
    for (int i = 0; i < 12; ++i) {
      float4 v = src[i];
      s += v.x + v.y + v.z + v.w;
      s2 += v.x * v.x + v.y * v.y + v.z * v.z + v.w * v.w;
      uint2 pk;
      pk.x = pk2bf(v.x, v.y);
      pk.y = pk2bf(v.z, v.w);
      int u = p * 6 + (i >> 1);
      *(uint2*)((char*)Atile + r * 384 + ((u ^ (r & 7)) << 4) + (i & 1) * 8) = pk;
    }
    s += __shfl_xor(s, 1); s2 += __shfl_xor(s2, 1);
    s += __shfl_xor(s, 2); s2 += __shfl_xor(s2, 2);
    if (p == 0) {
      float mu = s * (1.f / 192.f);
      stats[r * 2] = mu;
      stats[r * 2 + 1] = rsqrtf(s2 * (1.f / 192.f) - mu * mu + 1e-5f);
    }
  }
  __syncthreads();
  // ---- MFMA: wave = one N-quarter of 96 cols (w 0,1 -> k; w 2,3 -> v) ----
  int l15 = lane & 15, l4 = lane >> 4;
  f32x4 acc[4][6];
  #pragma unroll
  for (int a = 0; a < 4; ++a)
    #pragma unroll
    for (int b2 = 0; b2 < 6; ++b2) acc[a][b2] = (f32x4){0.f, 0.f, 0.f, 0.f};
  #pragma unroll
  for (int kk = 0; kk < 6; ++kk) {
    bf16x8 afr[4];
    #pragma unroll
    for (int mt = 0; mt < 4; ++mt) {
      int row = mt * 16 + l15;
      int u = kk * 4 + l4;
      afr[mt] = *(bf16x8*)((char*)Atile + row * 384 + ((u ^ (row & 7)) << 4));
    }
    bf16x8 bfr[6];
    #pragma unroll
    for (int nt = 0; nt < 6; ++nt) {
      int col = w * 96 + nt * 16 + l15;
      bfr[nt] = *(const bf16x8*)(wmodT + col * DD + kk * 32 + l4 * 8);
    }
    #pragma unroll
    for (int mt = 0; mt < 4; ++mt)
      #pragma unroll
      for (int nt = 0; nt < 6; ++nt)
        acc[mt][nt] = __builtin_amdgcn_mfma_f32_16x16x32_bf16(afr[mt], bfr[nt],
                                                              acc[mt][nt], 0, 0, 0);
  }
  // per-token LN stats into regs (row = mt*16 + l4*4 + j)
  float muv[4][4], rsv[4][4];
  #pragma unroll
  for (int mt = 0; mt < 4; ++mt)
    #pragma unroll
    for (int j = 0; j < 4; ++j) {
      int row = mt * 16 + l4 * 4 + j;
      muv[mt][j] = stats[row * 2];
      rsv[mt][j] = stats[row * 2 + 1];
    }
  __syncthreads();   // all fragment reads of Atile complete
  long bidx = tile_base / FF;
  int f0 = (int)(tile_base % FF);
  if (w < 2) {
    // ---- k: C-tile into Atile (swizzled) ----
    #pragma unroll
    for (int nt = 0; nt < 6; ++nt) {
      int col = w * 96 + nt * 16 + l15;
      float s1c = s1[col], s0c = s0[col];
      int u = col >> 3, ce = (col & 7) * 2;
      #pragma unroll
      for (int mt = 0; mt < 4; ++mt) {
        #pragma unroll
        for (int j = 0; j < 4; ++j) {
          int row = mt * 16 + l4 * 4 + j;
          u16 hv = f2bf(rsv[mt][j] * (acc[mt][nt][j] - muv[mt][j] * s1c) + s0c);
          *(u16*)((char*)Atile + row * 384 + ((u ^ (row & 7)) << 4) + ce) = hv;
        }
      }
    }
  } else {
    // ---- v: shfl-pack 8-token granules, direct global store (no LDS) ----
    #pragma unroll
    for (int nt = 0; nt < 6; ++nt) {
      int col = (w - 2) * 96 + nt * 16 + l15;   // v dim 0..191
      float s1c = s1[col + 192], s0c = s0[col + 192];
      int ntg = col >> 4;                        // == (w-2)*6 + nt
      #pragma unroll
      for (int mt = 0; mt < 4; ++mt) {
        int tl = mt * 16 + l4 * 4;               // local token of j=0
        uint2 pk;
        pk.x = pk2bf(rsv[mt][0] * (acc[mt][nt][0] - muv[mt][0] * s1c) + s0c,
                     rsv[mt][1] * (acc[mt][nt][1] - muv[mt][1] * s1c) + s0c);
        pk.y = pk2bf(rsv[mt][2] * (acc[mt][nt][2] - muv[mt][2] * s1c) + s0c,
                     rsv[mt][3] * (acc[mt][nt][3] - muv[mt][3] * s1c) + s0c);
        u32 ox = __shfl_xor((int)pk.x, 16);
        u32 oy = __shfl_xor((int)pk.y, 16);
        if ((l4 & 1) == 0) {
          int t0 = f0 + tl;                      // token of granule start (mult of 8)
          int g32 = t0 >> 5;
          int l4f = (t0 >> 3) & 3;
          uint4 val = {pk.x, pk.y, ox, oy};
          *(uint4*)(vc_ + ((((long)bidx * 128 + g32) * 12 + ntg) * 64 + l4f * 16 +
                           (col & 15)) * 8) = val;
        }
      }
    }
  }
  __syncthreads();
  // ---- k store: coalesced granules [Tg][u][tok16][8dims] ----
  {
    long Tg0 = tile_base >> 4;
    #pragma unroll
    for (int p2 = 0; p2 < 6; ++p2) {
      int fi = tid + p2 * 256;
      int tau = fi & 15, u = (fi >> 4) % 24, tt = fi / 384;
      uint4 val = *(uint4*)((char*)Atile + (tt * 16 + tau) * 384 + ((u ^ (tau & 7)) << 4));
      *(uint4*)(kc_ + (((Tg0 + tt) * 24 + u) * 16 + tau) * 8) = val;
    }
  }
}

// ---------------------------------------------------------------------------
// q projection: q = LN(slots) @ Wq * scale.  One wave per (b,k).
// ---------------------------------------------------------------------------
__global__ __launch_bounds__(64) void qproj_kernel(
    const float* __restrict__ slots, const float* __restrict__ Wq,
    const float* __restrict__ g, const float* __restrict__ bb,
    float* __restrict__ qbuf) {
  __shared__ float ln[192];
  int bk = blockIdx.x;
  int lane = threadIdx.x;
  const float* x = slots + bk * DD;
  float v0 = x[lane], v1 = x[lane + 64], v2 = x[lane + 128];
  float s = v0 + v1 + v2, s2 = v0 * v0 + v1 * v1 + v2 * v2;
  #pragma unroll
  for (int m = 1; m < 64; m <<= 1) { s += __shfl_xor(s, m); s2 += __shfl_xor(s2, m); }
  float mu = s * (1.f / 192.f);
  float rstd = rsqrtf(s2 * (1.f / 192.f) - mu * mu + 1e-5f);
  ln[lane]       = (v0 - mu) * rstd * g[lane]       + bb[lane];
  ln[lane + 64]  = (v1 - mu) * rstd * g[lane + 64]  + bb[lane + 64];
  ln[lane + 128] = (v2 - mu) * rstd * g[lane + 128] + bb[lane + 128];
  __syncthreads();
  float a0 = 0.f, a1 = 0.f, a2 = 0.f;
  for (int e = 0; e < DD; ++e) {
    float le = ln[e];
    a0 += le * Wq[e * DD + lane];
    a1 += le * Wq[e * DD + lane + 64];
    a2 += le * Wq[e * DD + lane + 128];
  }
  const float scale = 0.07216878364870323f;  // 192^-0.5
  qbuf[bk * DD + lane]       = a0 * scale;
  qbuf[bk * DD + lane + 64]  = a1 * scale;
  qbuf[bk * DD + lane + 128] = a2 * scale;
}

// ---------------------------------------------------------------------------
// Fused attention + update: QK^T (+bias) -> softmax over 8 -> attn to LDS ->
// PV MFMA -> atomicAdd partial updates.  grid (B, 16): 256 tokens per block.
// ---------------------------------------------------------------------------
__global__ __launch_bounds__(256) void attnupd_kernel(
    const u16* __restrict__ kc_, const u16* __restrict__ vc_,
    const float* __restrict__ qbuf,
    const float* __restrict__ asum_prev, const float* __restrict__ cacc_prev,
    float* __restrict__ upd, float* __restrict__ asum_cur,
    float* __restrict__ cacc_cur, int have_bias) {
  __shared__ __align__(16) u16 qlds[16 * 192];
  __shared__ __align__(16) u16 attn_lds[16 * 256];   // [slot][token], XOR-swizzled
  int b = blockIdx.x;
  int chunk = blockIdx.y * 256;
  int tid = threadIdx.x;
  if (tid < 192) {
    int s = tid / 24, u = tid % 24;
    const float* qp = qbuf + (b * 8 + s) * DD + u * 8;
    uint4 p;
    p.x = pk2bf(qp[0], qp[1]);
    p.y = pk2bf(qp[2], qp[3]);
    p.z = pk2bf(qp[4], qp[5]);
    p.w = pk2bf(qp[6], qp[7]);
    *(uint4*)((char*)qlds + s * 384 + ((u ^ (s & 7)) << 4)) = p;
  } else {
    int t2 = tid - 192;
    #pragma unroll
    for (int i = 0; i < 3; ++i) {
      int idx = t2 * 3 + i;      // 192 units of q rows 8..15
      int s = 8 + idx / 24, u = idx % 24;
      *(uint4*)((char*)qlds + s * 384 + ((u ^ (s & 7)) << 4)) = (uint4){0, 0, 0, 0};
    }
    // zero attn rows 8..15 (A-operand padding)
    #pragma unroll
    for (int i = 0; i < 4; ++i)
      *(uint4*)((char*)attn_lds + 4096 + (t2 * 4 + i) * 16) = (uint4){0, 0, 0, 0};
  }
  __syncthreads();
  int w = tid >> 6, lane = tid & 63;
  int l15 = lane & 15, l4 = lane >> 4;
  bf16x8 qfr[6];
  #pragma unroll
  for (int kk = 0; kk < 6; ++kk) {
    int u = kk * 4 + l4;
    qfr[kk] = *(bf16x8*)((char*)qlds + l15 * 384 + ((u ^ (l15 & 7)) << 4));
  }
  float ax[4], ay[4], c0[4];
  #pragma unroll
  for (int j = 0; j < 4; ++j) {
    int s = l4 * 4 + j;
    if (have_bias && s < 8) {
      float inv = 1.f / (asum_prev[b * 8 + s] + 1e-8f);
      float cx = cacc_prev[(b * 8 + s) * 2] * inv;
      float cy = cacc_prev[(b * 8 + s) * 2 + 1] * inv;
      ax[j] = 16.f * cx; ay[j] = 16.f * cy; c0[j] = -8.f * (cx * cx + cy * cy);
    } else { ax[j] = 0.f; ay[j] = 0.f; c0[j] = 0.f; }
  }
  float pa[4], px[4], py[4];
  #pragma unroll
  for (int j = 0; j < 4; ++j) { pa[j] = 0.f; px[j] = 0.f; py[j] = 0.f; }
  for (int tile = w; tile < 16; tile += 4) {
    int t0 = chunk + tile * 16;
    long Tg = (long)b * 256 + (t0 >> 4);
    const u16* kp = kc_ + (Tg * 24 + l4) * 128 + l15 * 8;
    f32x4 acc = (f32x4){0.f, 0.f, 0.f, 0.f};
    #pragma unroll
    for (int kk = 0; kk < 6; ++kk) {
      bf16x8 bfr = *(const bf16x8*)(kp + kk * 512);
      acc = __builtin_amdgcn_mfma_f32_16x16x32_bf16(qfr[kk], bfr, acc, 0, 0, 0);
    }
    int t = t0 + l15;
    float x = -1.f + (float)(t & 63) * (2.f / 63.f);
    float y = -1.f + (float)(t >> 6) * (2.f / 63.f);
    float m8r2 = -8.f * (x * x + y * y);
    float d4[4];
    #pragma unroll
    for (int j = 0; j < 4; ++j)
      d4[j] = acc[j] + (have_bias ? (ax[j] * x + ay[j] * y + c0[j] + m8r2) : 0.f);
    float o4[4];
    #pragma unroll
    for (int j = 0; j < 4; ++j) o4[j] = __shfl_xor(d4[j], 16);
    float mx = fmaxf(fmaxf(fmaxf(d4[0], d4[1]), fmaxf(d4[2], d4[3])),
                     fmaxf(fmaxf(o4[0], o4[1]), fmaxf(o4[2], o4[3])));
    float e4[4];
    float sum = 0.f;
    #pragma unroll
    for (int j = 0; j < 4; ++j) { e4[j] = __expf(d4[j] - mx); sum += e4[j]; }
    #pragma unroll
    for (int j = 0; j < 4; ++j) sum += __expf(o4[j] - mx);
    float inv = 1.f / sum;
    if (l4 < 2) {
      int tl = tile * 16 + l15;
      #pragma unroll
      for (int j = 0; j < 4; ++j) {
        float a = e4[j] * inv;
        int s = l4 * 4 + j;
        *(u16*)((char*)attn_lds + ((s * 512 + tl * 2) ^ ((s & 7) << 4))) = f2bf(a);
        pa[j] += a; px[j] += a * x; py[j] += a * y;
      }
    }
  }
  #pragma unroll
  for (int m = 1; m < 16; m <<= 1) {
    #pragma unroll
    for (int j = 0; j < 4; ++j) {
      pa[j] += __shfl_xor(pa[j], m);
      px[j] += __shfl_xor(px[j], m);
      py[j] += __shfl_xor(py[j], m);
    }
  }
  if (l15 == 0 && l4 < 2) {
    #pragma unroll
    for (int j = 0; j < 4; ++j) {
      int s = l4 * 4 + j;
      atomicAdd(&asum_cur[b * 8 + s], pa[j]);
      atomicAdd(&cacc_cur[(b * 8 + s) * 2], px[j]);
      atomicAdd(&cacc_cur[(b * 8 + s) * 2 + 1], py[j]);
    }
  }
  __syncthreads();
  // ---- PV: wave w handles nt = 3w..3w+2; K = 256 tokens (8 MFMA steps) ----
  int g32base = chunk >> 5;
  #pragma unroll
  for (int ni = 0; ni < 3; ++ni) {
    int nt = w * 3 + ni;
    f32x4 acc = (f32x4){0.f, 0.f, 0.f, 0.f};
    const u16* vp = vc_ + ((((long)b * 128 + g32base) * 12 + nt) * 64 + l4 * 16 + l15) * 8;
    #pragma unroll
    for (int gl = 0; gl < 8; ++gl) {
      int tl0 = gl * 32 + l4 * 8;
      bf16x8 afr = *(bf16x8*)((char*)attn_lds + ((l15 * 512 + tl0 * 2) ^ ((l15 & 7) << 4)));
      bf16x8 bfr = *(const bf16x8*)(vp + gl * 12 * 64 * 8);
      acc = __builtin_amdgcn_mfma_f32_16x16x32_bf16(afr, bfr, acc, 0, 0, 0);
    }
    if (l4 < 2) {
      #pragma unroll
      for (int j = 0; j < 4; ++j) {
        int s = l4 * 4 + j;
        atomicAdd(&upd[((long)b * 8 + s) * DD + nt * 16 + l15], acc[j]);
      }
    }
  }
}

// ---------------------------------------------------------------------------
// GRU + LN + MLP.  768 threads (12 waves), column-parallel phases, bf16 weights.
// grid (B, 4): y0: g0 slot0 (M=1); y1: g2 slot7 (M=1); y2: g1 slots1-3; y3: g1 slots4-6.
// ---------------------------------------------------------------------------
template <int M>
__device__ void gru_body(int b0, int g, int srow,
                         float* u_l, float* h_l, float* gi_l, float* gh_l,
                         float* hn_l, float* ln_l, float* x1_l, float* out_l, float* st,
                         const float* __restrict__ upd, const float* __restrict__ asum,
                         const float* __restrict__ sin_,
                         const u16* __restrict__ pWih, const u16* __restrict__ pWhh,
                         const float* __restrict__ bih, const float* __restrict__ bhh,
                         const float* __restrict__ mlng, const float* __restrict__ mlnb,
                         const u16* __restrict__ pW1, const float* __restrict__ b1,
                         const u16* __restrict__ pW2, const float* __restrict__ b2,
                         float* __restrict__ sout) {
  int tid = threadIdx.x;
  for (int idx = tid; idx < M * 192; idx += 768) {
    int row = idx / 192, d = idx % 192;
    int gr = b0 * 8 + srow + row;
    float inv = 1.f / (asum[gr] + 1e-8f);
    u_l[row * 192 + d] = upd[gr * DD + d] * inv;
    h_l[row * 192 + d] = sin_[gr * DD + d];
  }
  __syncthreads();
  // GRU gates: thread = output col c of [r|z|n]x192
  if (tid < 576) {
    int c = tid;
    const u16* wih = pWih + (size_t)g * 96 * 1152 + c * 2;
    const u16* whh = pWhh + (size_t)g * 96 * 1152 + c * 2;
    float ai[M], ah[M];
    #pragma unroll
    for (int r = 0; r < M; ++r) { ai[r] = 0.f; ah[r] = 0.f; }
    #pragma unroll 4
    for (int e2 = 0; e2 < 96; ++e2) {
      u32 wi = *(const u32*)(wih + e2 * 1152);
      u32 wh = *(const u32*)(whh + e2 * 1152);
      float wi0 = bf2f(wi & 0xffffu), wi1 = bf2f(wi >> 16);
      float wh0 = bf2f(wh & 0xffffu), wh1 = bf2f(wh >> 16);
      #pragma unroll
      for (int r = 0; r < M; ++r) {
        ai[r] += wi0 * u_l[r * 192 + e2 * 2] + wi1 * u_l[r * 192 + e2 * 2 + 1];
        ah[r] += wh0 * h_l[r * 192 + e2 * 2] + wh1 * h_l[r * 192 + e2 * 2 + 1];
      }
    }
    #pragma unroll
    for (int r = 0; r < M; ++r) { gi_l[r * 576 + c] = ai[r]; gh_l[r * 576 + c] = ah[r]; }
  }
  __syncthreads();
  // gate math
  if (tid < M * 192) {
    int row = tid / 192, uu = tid % 192;
    const float* bihg = bih + g * 576;
    const float* bhhg = bhh + g * 576;
    float r_ = sigm(gi_l[row * 576 + uu] + bihg[uu] + gh_l[row * 576 + uu] + bhhg[uu]);
    float z_ = sigm(gi_l[row * 576 + 192 + uu] + bihg[192 + uu] +
                    gh_l[row * 576 + 192 + uu] + bhhg[192 + uu]);
    float nn = gi_l[row * 576 + 384 + uu] + bihg[384 + uu] +
               r_ * (gh_l[row * 576 + 384 + uu] + bhhg[384 + uu]);
    float t = 1.f - 2.f / (__expf(2.f * nn) + 1.f);
    hn_l[row * 192 + uu] = (1.f - z_) * t + z_ * h_l[row * 192 + uu];
  }
  __syncthreads();
  // LN stats: wave per row
  {
    int wv = tid >> 6, lane = tid & 63;
    if (wv < M) {
      float v0 = hn_l[wv * 192 + lane], v1 = hn_l[wv * 192 + lane + 64],
            v2 = hn_l[wv * 192 + lane + 128];
      float s = v0 + v1 + v2, sq = v0 * v0 + v1 * v1 + v2 * v2;
      #pragma unroll
      for (int m = 1; m < 64; m <<= 1) { s += __shfl_xor(s, m); sq += __shfl_xor(sq, m); }
      if (lane == 0) {
        float mu = s * (1.f / 192.f);
        st[wv * 2] = mu;
        st[wv * 2 + 1] = rsqrtf(sq * (1.f / 192.f) - mu * mu + 1e-5f);
      }
    }
  }
  __syncthreads();
  if (tid < M * 192) {
    int row = tid / 192, uu = tid % 192;
    ln_l[row * 192 + uu] = (hn_l[row * 192 + uu] - st[row * 2]) * st[row * 2 + 1] *
                               mlng[g * DD + uu] + mlnb[g * DD + uu];
  }
  __syncthreads();
  // MLP1: thread = col c of 768
  {
    int c = tid;
    const u16* w1 = pW1 + (size_t)g * 96 * 1536 + c * 2;
    float a[M];
    #pragma unroll
    for (int r = 0; r < M; ++r) a[r] = 0.f;
    #pragma unroll 4
    for (int e2 = 0; e2 < 96; ++e2) {
      u32 wp = *(const u32*)(w1 + e2 * 1536);
      float w0 = bf2f(wp & 0xffffu), w1f = bf2f(wp >> 16);
      #pragma unroll
      for (int r = 0; r < M; ++r)
        a[r] += w0 * ln_l[r * 192 + e2 * 2] + w1f * ln_l[r * 192 + e2 * 2 + 1];
    }
    float bc = b1[g * HH + c];
    #pragma unroll
    for (int r = 0; r < M; ++r) x1_l[r * 768 + c] = fmaxf(a[r] + bc, 0.f);
  }
  if (tid < M * 192) {
    int row = tid / 192, uu = tid % 192;
    out_l[row * 192 + uu] = hn_l[row * 192 + uu] + b2[g * DD + uu];
  }
  __syncthreads();
  // MLP2: thread = (col c of 192, K-quarter ks)
  {
    int c = tid % 192, ks = tid / 192;
    const u16* w2 = pW2 + (size_t)g * 384 * 384 + c * 2;
    float a[M];
    #pragma unroll
    for (int r = 0; r < M; ++r) a[r] = 0.f;
    #pragma unroll 4
    for (int e2 = ks * 96; e2 < ks * 96 + 96; ++e2) {
      u32 wp = *(const u32*)(w2 + e2 * 384);
      float w0 = bf2f(wp & 0xffffu), w1f = bf2f(wp >> 16);
      #pragma unroll
      for (int r = 0; r < M; ++r)
        a[r] += w0 * x1_l[r * 768 + e2 * 2] + w1f * x1_l[r * 768 + e2 * 2 + 1];
    }
    #pragma unroll
    for (int r = 0; r < M; ++r) atomicAdd(&out_l[r * 192 + c], a[r]);
  }
  __syncthreads();
  if (tid < M * 192) {
    int row = tid / 192, d = tid % 192;
    sout[(b0 * 8 + srow + row) * DD + d] = out_l[row * 192 + d];
  }
}

__global__ __launch_bounds__(768) void gru_kernel(
    const float* __restrict__ upd, const float* __restrict__ asum,
    const float* __restrict__ sin_,
    const u16* __restrict__ pWih, const u16* __restrict__ pWhh,
    const float* __restrict__ bih, const float* __restrict__ bhh,
    const float* __restrict__ mlng, const float* __restrict__ mlnb,
    const u16* __restrict__ pW1, const float* __restrict__ b1,
    const u16* __restrict__ pW2, const float* __restrict__ b2,
    float* __restrict__ sout) {
  __shared__ float u_l[3 * 192], h_l[3 * 192], gi_l[3 * 576], gh_l[3 * 576];
  __shared__ float hn_l[3 * 192], ln_l[3 * 192], x1_l[3 * 768], out_l[3 * 192], st[8];
  int b = blockIdx.x, y = blockIdx.y;
  if (y == 0)
    gru_body<1>(b, 0, 0, u_l, h_l, gi_l, gh_l, hn_l, ln_l, x1_l, out_l, st,
                upd, asum, sin_, pWih, pWhh, bih, bhh, mlng, mlnb, pW1, b1, pW2, b2, sout);
  else if (y == 1)
    gru_body<1>(b, 2, 7, u_l, h_l, gi_l, gh_l, hn_l, ln_l, x1_l, out_l, st,
                upd, asum, sin_, pWih, pWhh, bih, bhh, mlng, mlnb, pW1, b1, pW2, b2, sout);
  else if (y == 2)
    gru_body<3>(b, 1, 1, u_l, h_l, gi_l, gh_l, hn_l, ln_l, x1_l, out_l, st,
                upd, asum, sin_, pWih, pWhh, bih, bhh, mlng, mlnb, pW1, b1, pW2, b2, sout);
  else
    gru_body<3>(b, 1, 4, u_l, h_l, gi_l, gh_l, hn_l, ln_l, x1_l, out_l, st,
                upd, asum, sin_, pWih, pWhh, bih, bhh, mlng, mlnb, pW1, b1, pW2, b2, sout);
}

// ---------------------------------------------------------------------------
extern "C" void kernel_launch(void* const* d_in, const int* in_sizes, int n_in,
                              void* d_out, int out_size, void* d_ws, size_t ws_size,
                              hipStream_t stream) {
  const float* feat = (const float*)d_in[0];
  const float* slots = (const float*)d_in[1];
  const float* Wk = (const float*)d_in[2];
  const float* Wv = (const float*)d_in[3];
  const float* Wq = (const float*)d_in[4];
  const float* lfg = (const float*)d_in[5];
  const float* lfb = (const float*)d_in[6];
  const float* lsg = (const float*)d_in[7];
  const float* lsb = (const float*)d_in[8];
  const float* gWih = (const float*)d_in[9];
  const float* gWhh = (const float*)d_in[10];
  const float* gbih = (const float*)d_in[11];
  const float* gbhh = (const float*)d_in[12];
  const float* mlng = (const float*)d_in[13];
  const float* mlnb = (const float*)d_in[14];
  const float* W1 = (const float*)d_in[15];
  const float* b1 = (const float*)d_in[16];
  const float* W2 = (const float*)d_in[17];
  const float* b2 = (const float*)d_in[18];
  float* out = (float*)d_out;

  char* ws = (char*)d_ws;
  size_t off = 0;
  auto alloc = [&](size_t bytes) {
    void* p = ws + off;
    off += (bytes + 255) & ~(size_t)255;
    return p;
  };
  u16* kc_    = (u16*)alloc((size_t)BB * FF * DD * 2);
  u16* vc_    = (u16*)alloc((size_t)BB * DD * FF * 2);
  float* qbuf = (float*)alloc((size_t)BB * 8 * DD * 4);
  float* upd  = (float*)alloc((size_t)BB * 8 * DD * 4);
  float* slA  = (float*)alloc((size_t)BB * 8 * DD * 4);
  float* slB  = (float*)alloc((size_t)BB * 8 * DD * 4);
  float* asum0 = (float*)alloc(BB * 8 * 4);
  float* asum1 = (float*)alloc(BB * 8 * 4);
  float* cacc0 = (float*)alloc(BB * 8 * 2 * 4);
  float* cacc1 = (float*)alloc(BB * 8 * 2 * 4);
  u16* wmodT  = (u16*)alloc(384 * DD * 2);
  float* s1   = (float*)alloc(384 * 4);
  float* s0   = (float*)alloc(384 * 4);
  u16* pWih   = (u16*)alloc((size_t)3 * 576 * DD * 2);
  u16* pWhh   = (u16*)alloc((size_t)3 * 576 * DD * 2);
  u16* pW1    = (u16*)alloc((size_t)3 * DD * HH * 2);
  u16* pW2    = (u16*)alloc((size_t)3 * HH * DD * 2);

  prep_wmod<<<6, 64, 0, stream>>>(Wk, Wv, lfg, lfb, wmodT, s1, s0);
  prep_packw<<<dim3(432, 4), 256, 0, stream>>>(gWih, gWhh, W1, W2, pWih, pWhh, pW1, pW2);
  proj_kernel<<<BB * FF / 64, 256, 0, stream>>>(feat, wmodT, s1, s0, kc_, vc_);

  const float* sin_ = slots;
  float* souts[3] = {slA, slB, out};
  float* asums[2] = {asum0, asum1};
  float* caccs[2] = {cacc0, cacc1};
  for (int it = 0; it < 3; ++it) {
    int cur = it & 1, prev = cur ^ 1;
    hipMemsetAsync(upd, 0, BB * 8 * DD * 4, stream);
    hipMemsetAsync(asums[cur], 0, BB * 8 * 4, stream);
    hipMemsetAsync(caccs[cur], 0, BB * 8 * 2 * 4, stream);
    qproj_kernel<<<BB * 8, 64, 0, stream>>>(sin_, Wq, lsg, lsb, qbuf);
    attnupd_kernel<<<dim3(BB, 16), 256, 0, stream>>>(kc_, vc_, qbuf, asums[prev],
                                                     caccs[prev], upd, asums[cur],
                                                     caccs[cur], it > 0 ? 1 : 0);
    gru_kernel<<<dim3(BB, 4), 768, 0, stream>>>(upd, asums[cur], sin_, pWih, pWhh,
                                                gbih, gbhh, mlng, mlnb, pW1, b1, pW2, b2,
                                                souts[it]);
    sin_ = souts[it];
  }
}

// Round 4
// 490.429 us; speedup vs baseline: 1.3187x; 1.3187x over previous
//
#include <hip/hip_runtime.h>

typedef unsigned short u16;
typedef unsigned int u32;

#define BB 64
#define FF 4096
#define DD 192
#define HH 768

typedef __attribute__((ext_vector_type(8))) __bf16 bf16x8;
typedef __attribute__((ext_vector_type(4))) float f32x4;

__device__ __forceinline__ float bf2f(u32 u) {
  union { u32 i; float f; } x; x.i = u << 16; return x.f;
}
__device__ __forceinline__ u16 f2bf(float f) {
  __bf16 h = (__bf16)f;
  return __builtin_bit_cast(u16, h);
}
__device__ __forceinline__ u32 pk2bf(float a, float b) {
  return (u32)f2bf(a) | ((u32)f2bf(b) << 16);
}
__device__ __forceinline__ float sigm(float x) { return 1.f / (1.f + __expf(-x)); }

// ---------------------------------------------------------------------------
// Prep: WmodT[n][e] = g[e]*W[e][n] (bf16), s1[n]=sum g*W (bf16-rounded), s0[n]=b@W.
// ---------------------------------------------------------------------------
__global__ void prep_wmod(const float* __restrict__ Wk, const float* __restrict__ Wv,
                          const float* __restrict__ g, const float* __restrict__ bb,
                          u16* __restrict__ wmodT, float* __restrict__ s1,
                          float* __restrict__ s0) {
  int n = blockIdx.x * 64 + threadIdx.x;  // 0..383
  const float* W = (n < DD) ? Wk : Wv;
  int col = (n < DD) ? n : n - DD;
  float a1 = 0.f, a0 = 0.f;
  for (int e = 0; e < DD; ++e) {
    float w = W[e * DD + col];
    u16 h = f2bf(g[e] * w);
    wmodT[n * DD + e] = h;
    a1 += bf2f(h);
    a0 += bb[e] * w;
  }
  s1[n] = a1; s0[n] = a0;
}

// Pack GRU/MLP weights to bf16 e-pairs: dst[((g*E2+e/2)*N + n)*2 + (e&1)].
__global__ void prep_packw(const float* __restrict__ Wih, const float* __restrict__ Whh,
                           const float* __restrict__ W1, const float* __restrict__ W2,
                           u16* __restrict__ pWih, u16* __restrict__ pWhh,
                           u16* __restrict__ pW1, u16* __restrict__ pW2) {
  int which = blockIdx.y;
  int total, N, E;
  const float* src; u16* dst; int srcEmajor;
  if (which < 2) { total = 3 * 576 * 192; N = 576; E = 192; srcEmajor = 0;
                   src = which ? Whh : Wih; dst = which ? pWhh : pWih; }
  else if (which == 2) { total = 3 * 192 * 768; N = 768; E = 192; srcEmajor = 1;
                         src = W1; dst = pW1; }
  else { total = 3 * 768 * 192; N = 192; E = 768; srcEmajor = 1; src = W2; dst = pW2; }
  for (int idx = blockIdx.x * 256 + threadIdx.x; idx < total; idx += gridDim.x * 256) {
    int g = idx / (N * E), rem = idx % (N * E);
    int n, e;
    if (srcEmajor) { e = rem / N; n = rem % N; }    // src[g][e][n]
    else { n = rem / E; e = rem % E; }              // src[g][n][e]
    dst[((g * (E / 2) + (e >> 1)) * N + n) * 2 + (e & 1)] = f2bf(src[idx]);
  }
}

// ---------------------------------------------------------------------------
// Projection: k = LN(x)@Wk, v = LN(x)@Wv, LN folded into epilogue.
// kc_: chunked fragment layout [(b*256+Tg)*24 + u][tok16][8dims] bf16.
// vc_: PV B-fragment layout [((b*128+g32)*12 + nt)*64 + l4*16 + l15][8toks] bf16.
// Block: 256 thr (4 waves), M-tile = 32 tokens; wave = one N-quarter (96 cols).
// acc[2][6] = 48 VGPRs -> fits 128-reg budget of (256,4) without spilling.
// ---------------------------------------------------------------------------
__global__ __launch_bounds__(256, 4) void proj_kernel(
    const float* __restrict__ feat, const u16* __restrict__ wmodT,
    const float* __restrict__ s1, const float* __restrict__ s0,
    u16* __restrict__ kc_, u16* __restrict__ vc_) {
  __shared__ __align__(16) u16 Atile[32 * 192];   // swizzled bf16; reused as k C-tile
  __shared__ float stats[32 * 2];                 // (mu, rstd)
  int tid = threadIdx.x;
  long tile_base = (long)blockIdx.x * 32;
  int w = tid >> 6, lane = tid & 63;
  // ---- staging: wave w owns rows w*8..+7; 8 lanes per row, shuffle stats ----
  {
    int r = w * 8 + (lane >> 3);
    int p = lane & 7;
    const float4* src = (const float4*)(feat + (tile_base + r) * DD) + p * 6;
    float s = 0.f, s2 = 0.f;
    #pragma unroll
    for (int i = 0; i < 6; ++i) {
      float4 v = src[i];
      s += v.x + v.y + v.z + v.w;
      s2 += v.x * v.x + v.y * v.y + v.z * v.z + v.w * v.w;
      uint2 pk;
      pk.x = pk2bf(v.x, v.y);
      pk.y = pk2bf(v.z, v.w);
      int u = p * 3 + (i >> 1);
      *(uint2*)((char*)Atile + r * 384 + ((u ^ (r & 7)) << 4) + (i & 1) * 8) = pk;
    }
    s += __shfl_xor(s, 1); s2 += __shfl_xor(s2, 1);
    s += __shfl_xor(s, 2); s2 += __shfl_xor(s2, 2);
    s += __shfl_xor(s, 4); s2 += __shfl_xor(s2, 4);
    if (p == 0) {
      float mu = s * (1.f / 192.f);
      stats[r * 2] = mu;
      stats[r * 2 + 1] = rsqrtf(s2 * (1.f / 192.f) - mu * mu + 1e-5f);
    }
  }
  __syncthreads();
  // ---- MFMA: wave = one N-quarter of 96 cols (w 0,1 -> k; w 2,3 -> v) ----
  int l15 = lane & 15, l4 = lane >> 4;
  f32x4 acc[2][6];
  #pragma unroll
  for (int a = 0; a < 2; ++a)
    #pragma unroll
    for (int b2 = 0; b2 < 6; ++b2) acc[a][b2] = (f32x4){0.f, 0.f, 0.f, 0.f};
  #pragma unroll
  for (int kk = 0; kk < 6; ++kk) {
    bf16x8 afr[2];
    #pragma unroll
    for (int mt = 0; mt < 2; ++mt) {
      int row = mt * 16 + l15;
      int u = kk * 4 + l4;
      afr[mt] = *(bf16x8*)((char*)Atile + row * 384 + ((u ^ (row & 7)) << 4));
    }
    bf16x8 bfr[6];
    #pragma unroll
    for (int nt = 0; nt < 6; ++nt) {
      int col = w * 96 + nt * 16 + l15;
      bfr[nt] = *(const bf16x8*)(wmodT + col * DD + kk * 32 + l4 * 8);
    }
    #pragma unroll
    for (int mt = 0; mt < 2; ++mt)
      #pragma unroll
      for (int nt = 0; nt < 6; ++nt)
        acc[mt][nt] = __builtin_amdgcn_mfma_f32_16x16x32_bf16(afr[mt], bfr[nt],
                                                              acc[mt][nt], 0, 0, 0);
  }
  __syncthreads();   // all fragment reads of Atile complete
  long bidx = tile_base / FF;
  int f0 = (int)(tile_base % FF);
  if (w < 2) {
    // ---- k: C-tile into Atile (swizzled); LN stats read from LDS ----
    #pragma unroll
    for (int nt = 0; nt < 6; ++nt) {
      int col = w * 96 + nt * 16 + l15;
      float s1c = s1[col], s0c = s0[col];
      int u = col >> 3, ce = (col & 7) * 2;
      #pragma unroll
      for (int mt = 0; mt < 2; ++mt) {
        #pragma unroll
        for (int j = 0; j < 4; ++j) {
          int row = mt * 16 + l4 * 4 + j;
          float mu = stats[row * 2], rstd = stats[row * 2 + 1];
          u16 hv = f2bf(rstd * (acc[mt][nt][j] - mu * s1c) + s0c);
          *(u16*)((char*)Atile + row * 384 + ((u ^ (row & 7)) << 4) + ce) = hv;
        }
      }
    }
  } else {
    // ---- v: shfl-pack 8-token granules, direct global store (no LDS) ----
    #pragma unroll
    for (int nt = 0; nt < 6; ++nt) {
      int col = (w - 2) * 96 + nt * 16 + l15;   // v dim 0..191
      float s1c = s1[col + 192], s0c = s0[col + 192];
      int ntg = col >> 4;                        // == (w-2)*6 + nt
      #pragma unroll
      for (int mt = 0; mt < 2; ++mt) {
        int tl = mt * 16 + l4 * 4;               // local token of j=0
        int r0 = tl, r1 = tl + 1, r2 = tl + 2, r3 = tl + 3;
        uint2 pk;
        pk.x = pk2bf(stats[r0 * 2 + 1] * (acc[mt][nt][0] - stats[r0 * 2] * s1c) + s0c,
                     stats[r1 * 2 + 1] * (acc[mt][nt][1] - stats[r1 * 2] * s1c) + s0c);
        pk.y = pk2bf(stats[r2 * 2 + 1] * (acc[mt][nt][2] - stats[r2 * 2] * s1c) + s0c,
                     stats[r3 * 2 + 1] * (acc[mt][nt][3] - stats[r3 * 2] * s1c) + s0c);
        u32 ox = __shfl_xor((int)pk.x, 16);
        u32 oy = __shfl_xor((int)pk.y, 16);
        if ((l4 & 1) == 0) {
          int t0 = f0 + tl;                      // token of granule start (mult of 8)
          int g32 = t0 >> 5;
          int l4f = (t0 >> 3) & 3;
          uint4 val = {pk.x, pk.y, ox, oy};
          *(uint4*)(vc_ + ((((long)bidx * 128 + g32) * 12 + ntg) * 64 + l4f * 16 +
                           (col & 15)) * 8) = val;
        }
      }
    }
  }
  __syncthreads();
  // ---- k store: coalesced granules [Tg][u][tok16][8dims]; 768 granules ----
  {
    long Tg0 = tile_base >> 4;
    #pragma unroll
    for (int p2 = 0; p2 < 3; ++p2) {
      int fi = tid + p2 * 256;
      int tau = fi & 15, u = (fi >> 4) % 24, tt = fi / 384;
      uint4 val = *(uint4*)((char*)Atile + (tt * 16 + tau) * 384 + ((u ^ (tau & 7)) << 4));
      *(uint4*)(kc_ + (((Tg0 + tt) * 24 + u) * 16 + tau) * 8) = val;
    }
  }
}

// ---------------------------------------------------------------------------
// q projection: q = LN(slots) @ Wq * scale.  One wave per (b,k).
// ---------------------------------------------------------------------------
__global__ __launch_bounds__(64) void qproj_kernel(
    const float* __restrict__ slots, const float* __restrict__ Wq,
    const float* __restrict__ g, const float* __restrict__ bb,
    float* __restrict__ qbuf) {
  __shared__ float ln[192];
  int bk = blockIdx.x;
  int lane = threadIdx.x;
  const float* x = slots + bk * DD;
  float v0 = x[lane], v1 = x[lane + 64], v2 = x[lane + 128];
  float s = v0 + v1 + v2, s2 = v0 * v0 + v1 * v1 + v2 * v2;
  #pragma unroll
  for (int m = 1; m < 64; m <<= 1) { s += __shfl_xor(s, m); s2 += __shfl_xor(s2, m); }
  float mu = s * (1.f / 192.f);
  float rstd = rsqrtf(s2 * (1.f / 192.f) - mu * mu + 1e-5f);
  ln[lane]       = (v0 - mu) * rstd * g[lane]       + bb[lane];
  ln[lane + 64]  = (v1 - mu) * rstd * g[lane + 64]  + bb[lane + 64];
  ln[lane + 128] = (v2 - mu) * rstd * g[lane + 128] + bb[lane + 128];
  __syncthreads();
  float a0 = 0.f, a1 = 0.f, a2 = 0.f;
  for (int e = 0; e < DD; ++e) {
    float le = ln[e];
    a0 += le * Wq[e * DD + lane];
    a1 += le * Wq[e * DD + lane + 64];
    a2 += le * Wq[e * DD + lane + 128];
  }
  const float scale = 0.07216878364870323f;  // 192^-0.5
  qbuf[bk * DD + lane]       = a0 * scale;
  qbuf[bk * DD + lane + 64]  = a1 * scale;
  qbuf[bk * DD + lane + 128] = a2 * scale;
}

// ---------------------------------------------------------------------------
// Fused attention + update: QK^T (+bias) -> softmax over 8 -> attn to LDS ->
// PV MFMA -> atomicAdd partial updates.  grid (B, 16): 256 tokens per block.
// ---------------------------------------------------------------------------
__global__ __launch_bounds__(256) void attnupd_kernel(
    const u16* __restrict__ kc_, const u16* __restrict__ vc_,
    const float* __restrict__ qbuf,
    const float* __restrict__ asum_prev, const float* __restrict__ cacc_prev,
    float* __restrict__ upd, float* __restrict__ asum_cur,
    float* __restrict__ cacc_cur, int have_bias) {
  __shared__ __align__(16) u16 qlds[16 * 192];
  __shared__ __align__(16) u16 attn_lds[16 * 256];   // [slot][token], XOR-swizzled
  int b = blockIdx.x;
  int chunk = blockIdx.y * 256;
  int tid = threadIdx.x;
  if (tid < 192) {
    int s = tid / 24, u = tid % 24;
    const float* qp = qbuf + (b * 8 + s) * DD + u * 8;
    uint4 p;
    p.x = pk2bf(qp[0], qp[1]);
    p.y = pk2bf(qp[2], qp[3]);
    p.z = pk2bf(qp[4], qp[5]);
    p.w = pk2bf(qp[6], qp[7]);
    *(uint4*)((char*)qlds + s * 384 + ((u ^ (s & 7)) << 4)) = p;
  } else {
    int t2 = tid - 192;
    #pragma unroll
    for (int i = 0; i < 3; ++i) {
      int idx = t2 * 3 + i;      // 192 units of q rows 8..15
      int s = 8 + idx / 24, u = idx % 24;
      *(uint4*)((char*)qlds + s * 384 + ((u ^ (s & 7)) << 4)) = (uint4){0, 0, 0, 0};
    }
    // zero attn rows 8..15 (A-operand padding)
    #pragma unroll
    for (int i = 0; i < 4; ++i)
      *(uint4*)((char*)attn_lds + 4096 + (t2 * 4 + i) * 16) = (uint4){0, 0, 0, 0};
  }
  __syncthreads();
  int w = tid >> 6, lane = tid & 63;
  int l15 = lane & 15, l4 = lane >> 4;
  bf16x8 qfr[6];
  #pragma unroll
  for (int kk = 0; kk < 6; ++kk) {
    int u = kk * 4 + l4;
    qfr[kk] = *(bf16x8*)((char*)qlds + l15 * 384 + ((u ^ (l15 & 7)) << 4));
  }
  float ax[4], ay[4], c0[4];
  #pragma unroll
  for (int j = 0; j < 4; ++j) {
    int s = l4 * 4 + j;
    if (have_bias && s < 8) {
      float inv = 1.f / (asum_prev[b * 8 + s] + 1e-8f);
      float cx = cacc_prev[(b * 8 + s) * 2] * inv;
      float cy = cacc_prev[(b * 8 + s) * 2 + 1] * inv;
      ax[j] = 16.f * cx; ay[j] = 16.f * cy; c0[j] = -8.f * (cx * cx + cy * cy);
    } else { ax[j] = 0.f; ay[j] = 0.f; c0[j] = 0.f; }
  }
  float pa[4], px[4], py[4];
  #pragma unroll
  for (int j = 0; j < 4; ++j) { pa[j] = 0.f; px[j] = 0.f; py[j] = 0.f; }
  for (int tile = w; tile < 16; tile += 4) {
    int t0 = chunk + tile * 16;
    long Tg = (long)b * 256 + (t0 >> 4);
    const u16* kp = kc_ + (Tg * 24 + l4) * 128 + l15 * 8;
    f32x4 acc = (f32x4){0.f, 0.f, 0.f, 0.f};
    #pragma unroll
    for (int kk = 0; kk < 6; ++kk) {
      bf16x8 bfr = *(const bf16x8*)(kp + kk * 512);
      acc = __builtin_amdgcn_mfma_f32_16x16x32_bf16(qfr[kk], bfr, acc, 0, 0, 0);
    }
    int t = t0 + l15;
    float x = -1.f + (float)(t & 63) * (2.f / 63.f);
    float y = -1.f + (float)(t >> 6) * (2.f / 63.f);
    float m8r2 = -8.f * (x * x + y * y);
    float d4[4];
    #pragma unroll
    for (int j = 0; j < 4; ++j)
      d4[j] = acc[j] + (have_bias ? (ax[j] * x + ay[j] * y + c0[j] + m8r2) : 0.f);
    float o4[4];
    #pragma unroll
    for (int j = 0; j < 4; ++j) o4[j] = __shfl_xor(d4[j], 16);
    float mx = fmaxf(fmaxf(fmaxf(d4[0], d4[1]), fmaxf(d4[2], d4[3])),
                     fmaxf(fmaxf(o4[0], o4[1]), fmaxf(o4[2], o4[3])));
    float e4[4];
    float sum = 0.f;
    #pragma unroll
    for (int j = 0; j < 4; ++j) { e4[j] = __expf(d4[j] - mx); sum += e4[j]; }
    #pragma unroll
    for (int j = 0; j < 4; ++j) sum += __expf(o4[j] - mx);
    float inv = 1.f / sum;
    if (l4 < 2) {
      int tl = tile * 16 + l15;
      #pragma unroll
      for (int j = 0; j < 4; ++j) {
        float a = e4[j] * inv;
        int s = l4 * 4 + j;
        *(u16*)((char*)attn_lds + ((s * 512 + tl * 2) ^ ((s & 7) << 4))) = f2bf(a);
        pa[j] += a; px[j] += a * x; py[j] += a * y;
      }
    }
  }
  #pragma unroll
  for (int m = 1; m < 16; m <<= 1) {
    #pragma unroll
    for (int j = 0; j < 4; ++j) {
      pa[j] += __shfl_xor(pa[j], m);
      px[j] += __shfl_xor(px[j], m);
      py[j] += __shfl_xor(py[j], m);
    }
  }
  if (l15 == 0 && l4 < 2) {
    #pragma unroll
    for (int j = 0; j < 4; ++j) {
      int s = l4 * 4 + j;
      atomicAdd(&asum_cur[b * 8 + s], pa[j]);
      atomicAdd(&cacc_cur[(b * 8 + s) * 2], px[j]);
      atomicAdd(&cacc_cur[(b * 8 + s) * 2 + 1], py[j]);
    }
  }
  __syncthreads();
  // ---- PV: wave w handles nt = 3w..3w+2; K = 256 tokens (8 MFMA steps) ----
  int g32base = chunk >> 5;
  #pragma unroll
  for (int ni = 0; ni < 3; ++ni) {
    int nt = w * 3 + ni;
    f32x4 acc = (f32x4){0.f, 0.f, 0.f, 0.f};
    const u16* vp = vc_ + ((((long)b * 128 + g32base) * 12 + nt) * 64 + l4 * 16 + l15) * 8;
    #pragma unroll
    for (int gl = 0; gl < 8; ++gl) {
      int tl0 = gl * 32 + l4 * 8;
      bf16x8 afr = *(bf16x8*)((char*)attn_lds + ((l15 * 512 + tl0 * 2) ^ ((l15 & 7) << 4)));
      bf16x8 bfr = *(const bf16x8*)(vp + gl * 12 * 64 * 8);
      acc = __builtin_amdgcn_mfma_f32_16x16x32_bf16(afr, bfr, acc, 0, 0, 0);
    }
    if (l4 < 2) {
      #pragma unroll
      for (int j = 0; j < 4; ++j) {
        int s = l4 * 4 + j;
        atomicAdd(&upd[((long)b * 8 + s) * DD + nt * 16 + l15], acc[j]);
      }
    }
  }
}

// ---------------------------------------------------------------------------
// GRU + LN + MLP.  768 threads (12 waves), column-parallel phases, bf16 weights.
// grid (B, 4): y0: g0 slot0 (M=1); y1: g2 slot7 (M=1); y2: g1 slots1-3; y3: g1 slots4-6.
// ---------------------------------------------------------------------------
template <int M>
__device__ void gru_body(int b0, int g, int srow,
                         float* u_l, float* h_l, float* gi_l, float* gh_l,
                         float* hn_l, float* ln_l, float* x1_l, float* out_l, float* st,
                         const float* __restrict__ upd, const float* __restrict__ asum,
                         const float* __restrict__ sin_,
                         const u16* __restrict__ pWih, const u16* __restrict__ pWhh,
                         const float* __restrict__ bih, const float* __restrict__ bhh,
                         const float* __restrict__ mlng, const float* __restrict__ mlnb,
                         const u16* __restrict__ pW1, const float* __restrict__ b1,
                         const u16* __restrict__ pW2, const float* __restrict__ b2,
                         float* __restrict__ sout) {
  int tid = threadIdx.x;
  for (int idx = tid; idx < M * 192; idx += 768) {
    int row = idx / 192, d = idx % 192;
    int gr = b0 * 8 + srow + row;
    float inv = 1.f / (asum[gr] + 1e-8f);
    u_l[row * 192 + d] = upd[gr * DD + d] * inv;
    h_l[row * 192 + d] = sin_[gr * DD + d];
  }
  __syncthreads();
  // GRU gates: thread = output col c of [r|z|n]x192
  if (tid < 576) {
    int c = tid;
    const u16* wih = pWih + (size_t)g * 96 * 1152 + c * 2;
    const u16* whh = pWhh + (size_t)g * 96 * 1152 + c * 2;
    float ai[M], ah[M];
    #pragma unroll
    for (int r = 0; r < M; ++r) { ai[r] = 0.f; ah[r] = 0.f; }
    #pragma unroll 4
    for (int e2 = 0; e2 < 96; ++e2) {
      u32 wi = *(const u32*)(wih + e2 * 1152);
      u32 wh = *(const u32*)(whh + e2 * 1152);
      float wi0 = bf2f(wi & 0xffffu), wi1 = bf2f(wi >> 16);
      float wh0 = bf2f(wh & 0xffffu), wh1 = bf2f(wh >> 16);
      #pragma unroll
      for (int r = 0; r < M; ++r) {
        ai[r] += wi0 * u_l[r * 192 + e2 * 2] + wi1 * u_l[r * 192 + e2 * 2 + 1];
        ah[r] += wh0 * h_l[r * 192 + e2 * 2] + wh1 * h_l[r * 192 + e2 * 2 + 1];
      }
    }
    #pragma unroll
    for (int r = 0; r < M; ++r) { gi_l[r * 576 + c] = ai[r]; gh_l[r * 576 + c] = ah[r]; }
  }
  __syncthreads();
  // gate math
  if (tid < M * 192) {
    int row = tid / 192, uu = tid % 192;
    const float* bihg = bih + g * 576;
    const float* bhhg = bhh + g * 576;
    float r_ = sigm(gi_l[row * 576 + uu] + bihg[uu] + gh_l[row * 576 + uu] + bhhg[uu]);
    float z_ = sigm(gi_l[row * 576 + 192 + uu] + bihg[192 + uu] +
                    gh_l[row * 576 + 192 + uu] + bhhg[192 + uu]);
    float nn = gi_l[row * 576 + 384 + uu] + bihg[384 + uu] +
               r_ * (gh_l[row * 576 + 384 + uu] + bhhg[384 + uu]);
    float t = 1.f - 2.f / (__expf(2.f * nn) + 1.f);
    hn_l[row * 192 + uu] = (1.f - z_) * t + z_ * h_l[row * 192 + uu];
  }
  __syncthreads();
  // LN stats: wave per row
  {
    int wv = tid >> 6, lane = tid & 63;
    if (wv < M) {
      float v0 = hn_l[wv * 192 + lane], v1 = hn_l[wv * 192 + lane + 64],
            v2 = hn_l[wv * 192 + lane + 128];
      float s = v0 + v1 + v2, sq = v0 * v0 + v1 * v1 + v2 * v2;
      #pragma unroll
      for (int m = 1; m < 64; m <<= 1) { s += __shfl_xor(s, m); sq += __shfl_xor(sq, m); }
      if (lane == 0) {
        float mu = s * (1.f / 192.f);
        st[wv * 2] = mu;
        st[wv * 2 + 1] = rsqrtf(sq * (1.f / 192.f) - mu * mu + 1e-5f);
      }
    }
  }
  __syncthreads();
  if (tid < M * 192) {
    int row = tid / 192, uu = tid % 192;
    ln_l[row * 192 + uu] = (hn_l[row * 192 + uu] - st[row * 2]) * st[row * 2 + 1] *
                               mlng[g * DD + uu] + mlnb[g * DD + uu];
  }
  __syncthreads();
  // MLP1: thread = col c of 768
  {
    int c = tid;
    const u16* w1 = pW1 + (size_t)g * 96 * 1536 + c * 2;
    float a[M];
    #pragma unroll
    for (int r = 0; r < M; ++r) a[r] = 0.f;
    #pragma unroll 4
    for (int e2 = 0; e2 < 96; ++e2) {
      u32 wp = *(const u32*)(w1 + e2 * 1536);
      float w0 = bf2f(wp & 0xffffu), w1f = bf2f(wp >> 16);
      #pragma unroll
      for (int r = 0; r < M; ++r)
        a[r] += w0 * ln_l[r * 192 + e2 * 2] + w1f * ln_l[r * 192 + e2 * 2 + 1];
    }
    float bc = b1[g * HH + c];
    #pragma unroll
    for (int r = 0; r < M; ++r) x1_l[r * 768 + c] = fmaxf(a[r] + bc, 0.f);
  }
  if (tid < M * 192) {
    int row = tid / 192, uu = tid % 192;
    out_l[row * 192 + uu] = hn_l[row * 192 + uu] + b2[g * DD + uu];
  }
  __syncthreads();
  // MLP2: thread = (col c of 192, K-quarter ks)
  {
    int c = tid % 192, ks = tid / 192;
    const u16* w2 = pW2 + (size_t)g * 384 * 384 + c * 2;
    float a[M];
    #pragma unroll
    for (int r = 0; r < M; ++r) a[r] = 0.f;
    #pragma unroll 4
    for (int e2 = ks * 96; e2 < ks * 96 + 96; ++e2) {
      u32 wp = *(const u32*)(w2 + e2 * 384);
      float w0 = bf2f(wp & 0xffffu), w1f = bf2f(wp >> 16);
      #pragma unroll
      for (int r = 0; r < M; ++r)
        a[r] += w0 * x1_l[r * 768 + e2 * 2] + w1f * x1_l[r * 768 + e2 * 2 + 1];
    }
    #pragma unroll
    for (int r = 0; r < M; ++r) atomicAdd(&out_l[r * 192 + c], a[r]);
  }
  __syncthreads();
  if (tid < M * 192) {
    int row = tid / 192, d = tid % 192;
    sout[(b0 * 8 + srow + row) * DD + d] = out_l[row * 192 + d];
  }
}

__global__ __launch_bounds__(768) void gru_kernel(
    const float* __restrict__ upd, const float* __restrict__ asum,
    const float* __restrict__ sin_,
    const u16* __restrict__ pWih, const u16* __restrict__ pWhh,
    const float* __restrict__ bih, const float* __restrict__ bhh,
    const float* __restrict__ mlng, const float* __restrict__ mlnb,
    const u16* __restrict__ pW1, const float* __restrict__ b1,
    const u16* __restrict__ pW2, const float* __restrict__ b2,
    float* __restrict__ sout) {
  __shared__ float u_l[3 * 192], h_l[3 * 192], gi_l[3 * 576], gh_l[3 * 576];
  __shared__ float hn_l[3 * 192], ln_l[3 * 192], x1_l[3 * 768], out_l[3 * 192], st[8];
  int b = blockIdx.x, y = blockIdx.y;
  if (y == 0)
    gru_body<1>(b, 0, 0, u_l, h_l, gi_l, gh_l, hn_l, ln_l, x1_l, out_l, st,
                upd, asum, sin_, pWih, pWhh, bih, bhh, mlng, mlnb, pW1, b1, pW2, b2, sout);
  else if (y == 1)
    gru_body<1>(b, 2, 7, u_l, h_l, gi_l, gh_l, hn_l, ln_l, x1_l, out_l, st,
                upd, asum, sin_, pWih, pWhh, bih, bhh, mlng, mlnb, pW1, b1, pW2, b2, sout);
  else if (y == 2)
    gru_body<3>(b, 1, 1, u_l, h_l, gi_l, gh_l, hn_l, ln_l, x1_l, out_l, st,
                upd, asum, sin_, pWih, pWhh, bih, bhh, mlng, mlnb, pW1, b1, pW2, b2, sout);
  else
    gru_body<3>(b, 1, 4, u_l, h_l, gi_l, gh_l, hn_l, ln_l, x1_l, out_l, st,
                upd, asum, sin_, pWih, pWhh, bih, bhh, mlng, mlnb, pW1, b1, pW2, b2, sout);
}

// ---------------------------------------------------------------------------
extern "C" void kernel_launch(void* const* d_in, const int* in_sizes, int n_in,
                              void* d_out, int out_size, void* d_ws, size_t ws_size,
                              hipStream_t stream) {
  const float* feat = (const float*)d_in[0];
  const float* slots = (const float*)d_in[1];
  const float* Wk = (const float*)d_in[2];
  const float* Wv = (const float*)d_in[3];
  const float* Wq = (const float*)d_in[4];
  const float* lfg = (const float*)d_in[5];
  const float* lfb = (const float*)d_in[6];
  const float* lsg = (const float*)d_in[7];
  const float* lsb = (const float*)d_in[8];
  const float* gWih = (const float*)d_in[9];
  const float* gWhh = (const float*)d_in[10];
  const float* gbih = (const float*)d_in[11];
  const float* gbhh = (const float*)d_in[12];
  const float* mlng = (const float*)d_in[13];
  const float* mlnb = (const float*)d_in[14];
  const float* W1 = (const float*)d_in[15];
  const float* b1 = (const float*)d_in[16];
  const float* W2 = (const float*)d_in[17];
  const float* b2 = (const float*)d_in[18];
  float* out = (float*)d_out;

  char* ws = (char*)d_ws;
  size_t off = 0;
  auto alloc = [&](size_t bytes) {
    void* p = ws + off;
    off += (bytes + 255) & ~(size_t)255;
    return p;
  };
  u16* kc_    = (u16*)alloc((size_t)BB * FF * DD * 2);
  u16* vc_    = (u16*)alloc((size_t)BB * DD * FF * 2);
  float* qbuf = (float*)alloc((size_t)BB * 8 * DD * 4);
  float* upd  = (float*)alloc((size_t)BB * 8 * DD * 4);
  float* slA  = (float*)alloc((size_t)BB * 8 * DD * 4);
  float* slB  = (float*)alloc((size_t)BB * 8 * DD * 4);
  float* asum0 = (float*)alloc(BB * 8 * 4);
  float* asum1 = (float*)alloc(BB * 8 * 4);
  float* cacc0 = (float*)alloc(BB * 8 * 2 * 4);
  float* cacc1 = (float*)alloc(BB * 8 * 2 * 4);
  u16* wmodT  = (u16*)alloc(384 * DD * 2);
  float* s1   = (float*)alloc(384 * 4);
  float* s0   = (float*)alloc(384 * 4);
  u16* pWih   = (u16*)alloc((size_t)3 * 576 * DD * 2);
  u16* pWhh   = (u16*)alloc((size_t)3 * 576 * DD * 2);
  u16* pW1    = (u16*)alloc((size_t)3 * DD * HH * 2);
  u16* pW2    = (u16*)alloc((size_t)3 * HH * DD * 2);

  prep_wmod<<<6, 64, 0, stream>>>(Wk, Wv, lfg, lfb, wmodT, s1, s0);
  prep_packw<<<dim3(432, 4), 256, 0, stream>>>(gWih, gWhh, W1, W2, pWih, pWhh, pW1, pW2);
  proj_kernel<<<BB * FF / 32, 256, 0, stream>>>(feat, wmodT, s1, s0, kc_, vc_);

  const float* sin_ = slots;
  float* souts[3] = {slA, slB, out};
  float* asums[2] = {asum0, asum1};
  float* caccs[2] = {cacc0, cacc1};
  for (int it = 0; it < 3; ++it) {
    int cur = it & 1, prev = cur ^ 1;
    hipMemsetAsync(upd, 0, BB * 8 * DD * 4, stream);
    hipMemsetAsync(asums[cur], 0, BB * 8 * 4, stream);
    hipMemsetAsync(caccs[cur], 0, BB * 8 * 2 * 4, stream);
    qproj_kernel<<<BB * 8, 64, 0, stream>>>(sin_, Wq, lsg, lsb, qbuf);
    attnupd_kernel<<<dim3(BB, 16), 256, 0, stream>>>(kc_, vc_, qbuf, asums[prev],
                                                     caccs[prev], upd, asums[cur],
                                                     caccs[cur], it > 0 ? 1 : 0);
    gru_kernel<<<dim3(BB, 4), 768, 0, stream>>>(upd, asums[cur], sin_, pWih, pWhh,
                                                gbih, gbhh, mlng, mlnb, pW1, b1, pW2, b2,
                                                souts[it]);
    sin_ = souts[it];
  }
}